// Round 2
// baseline (310.292 us; speedup 1.0000x reference)
//
#include <hip/hip_runtime.h>

typedef __bf16 bf16;
typedef __bf16 bf16x8 __attribute__((ext_vector_type(8)));
typedef float  f32x4  __attribute__((ext_vector_type(4)));

#define MFMA16(a, b, c) __builtin_amdgcn_mfma_f32_16x16x32_bf16((a), (b), (c), 0, 0, 0)

// One block per batch element. 256 threads = 4 waves; wave w owns k-rows [32w,32w+32).
// LDS ~23KB -> 5 blocks/CU with __launch_bounds__(256,5).
// tmsg/GEMM1 eliminated algebraically (piecewise rank-2), base exact fp32 in regs.
// 6 barriers total: stage, phaseB, 3 iters (partMu ping-pong), pooled.
__global__ __launch_bounds__(256, 5)
void qnet_kernel(const float* __restrict__ Xg, const float* __restrict__ Wg,
                 const float* __restrict__ W1g, const float* __restrict__ W2g,
                 const float* __restrict__ W3g, const float* __restrict__ W4g,
                 const float* __restrict__ W5g, const float* __restrict__ W6g,
                 const float* __restrict__ W7g, float* __restrict__ Outg)
{
    __shared__ __align__(16) bf16 muS[128 * 72];   // mu, bf16, row stride 72 (b128-aligned rows)
    __shared__ float xs[128], wws[128], W5s[128];
    __shared__ float partMu[2][256];               // ping-pong per-wave column sums
    __shared__ float partA[256], partB[256];
    __shared__ float uS[64];

    const int t    = threadIdx.x;
    const int b    = blockIdx.x;
    const int lane = t & 63;
    const int w    = t >> 6;
    const int l15  = lane & 15;
    const int quad = lane >> 4;

    // ---------------- stage per-batch vectors ----------------
    if (t < 128) { xs[t] = Xg[b * 128 + t]; W5s[t] = W5g[t]; }
    else         wws[t - 128] = Wg[b * 128 + t - 128];
    __syncthreads();

    // ---------------- phase B: closed-form tmsg terms (exact fp32) ----------------
    // Ap = sum_k max(w_k,0), Bn = sum_k max(-w_k,0)  (redundant per wave, butterfly)
    float Ap, Bn;
    {
        float w0 = wws[lane], w1 = wws[64 + lane];
        Ap = fmaxf(w0, 0.f) + fmaxf(w1, 0.f);
        Bn = fmaxf(-w0, 0.f) + fmaxf(-w1, 0.f);
#pragma unroll
        for (int m = 1; m < 64; m <<= 1) { Ap += __shfl_xor(Ap, m); Bn += __shfl_xor(Bn, m); }
    }

    // relu(+/-W4) slice for p = quad*16 + i
    float r4p[16], r4m[16];
#pragma unroll
    for (int c = 0; c < 4; ++c) {
        f32x4 v = *(const f32x4*)&W4g[quad * 16 + c * 4];
#pragma unroll
        for (int e = 0; e < 4; ++e) { r4p[c*4+e] = fmaxf(v[e], 0.f); r4m[c*4+e] = fmaxf(-v[e], 0.f); }
    }

    // v3p[q]=relu(W4)@W3[q,:], v3m[q]=relu(-W4)@W3[q,:]; st3[q]=Ap*v3p+Bn*v3m (= sum_t@W3^T)
    float v3p[4], v3m[4], st3[4], W1r[4];
#pragma unroll
    for (int qt = 0; qt < 4; ++qt) {
        const int q = qt * 16 + l15;
        float sp = 0.f, sm = 0.f;
#pragma unroll
        for (int c = 0; c < 4; ++c) {
            f32x4 wv = *(const f32x4*)&W3g[q * 64 + quad * 16 + c * 4];
#pragma unroll
            for (int e = 0; e < 4; ++e) { sp += r4p[c*4+e] * wv[e]; sm += r4m[c*4+e] * wv[e]; }
        }
        sp += __shfl_xor(sp, 16); sp += __shfl_xor(sp, 32);
        sm += __shfl_xor(sm, 16); sm += __shfl_xor(sm, 32);
        v3p[qt] = sp; v3m[qt] = sm;
        st3[qt] = Ap * sp + Bn * sm;
        W1r[qt] = W1g[q];
    }

    // u = W5b @ W7 partials (q-slice per wave)
    {
        float su = 0.f;
#pragma unroll
        for (int i = 0; i < 16; ++i)
            su += W5s[64 + w * 16 + i] * W7g[(w * 16 + i) * 64 + lane];
        partB[w * 64 + lane] = su;
    }

    // W2 B-fragments (bf16) straight from global (L1/L2-hot, shared by all blocks)
    bf16x8 bW2[4][2];
#pragma unroll
    for (int qt = 0; qt < 4; ++qt)
#pragma unroll
        for (int s = 0; s < 2; ++s) {
            f32x4 f0 = *(const f32x4*)&W2g[(qt * 16 + l15) * 64 + s * 32 + quad * 8];
            f32x4 f1 = *(const f32x4*)&W2g[(qt * 16 + l15) * 64 + s * 32 + quad * 8 + 4];
            bf16x8 h;
#pragma unroll
            for (int e = 0; e < 4; ++e) { h[e] = (bf16)f0[e]; h[4 + e] = (bf16)f1[e]; }
            bW2[qt][s] = h;
        }

    // mu1 = relu(base), base exact fp32 in registers (C-fragment layout)
    float baseR[2][4][4];
    {
        float psum[4] = {0.f, 0.f, 0.f, 0.f};
#pragma unroll
        for (int kt = 0; kt < 2; ++kt) {
            float xk[4], ak[4], bk[4];
#pragma unroll
            for (int r = 0; r < 4; ++r) {
                const int k = w * 32 + kt * 16 + quad * 4 + r;
                xk[r] = xs[k];
                float wk = wws[k];
                ak[r] = fmaxf(wk, 0.f); bk[r] = fmaxf(-wk, 0.f);
            }
#pragma unroll
            for (int qt = 0; qt < 4; ++qt)
#pragma unroll
                for (int r = 0; r < 4; ++r) {
                    float bb = xk[r] * W1r[qt] + st3[qt] - (ak[r] * v3p[qt] + bk[r] * v3m[qt]);
                    baseR[kt][qt][r] = bb;
                    bf16 h = (bf16)fmaxf(bb, 0.f);
                    const int k = w * 32 + kt * 16 + quad * 4 + r;
                    muS[k * 72 + qt * 16 + l15] = h;
                    psum[qt] += (float)h;
                }
        }
#pragma unroll
        for (int qt = 0; qt < 4; ++qt) {
            float p = psum[qt];
            p += __shfl_xor(p, 16); p += __shfl_xor(p, 32);
            if (lane < 16) partMu[0][w * 64 + qt * 16 + lane] = p;
        }
    }
    __syncthreads();

    // ---------------- 3 message-passing iterations, ONE barrier each ----------------
    const f32x4 zero4 = {0.f, 0.f, 0.f, 0.f};
    for (int it = 0; it < 3; ++it) {
        const float* pm  = partMu[it & 1];
        float*       pmN = partMu[(it + 1) & 1];
        if (it == 0 && t < 64)
            uS[t] = partB[t] + partB[64 + t] + partB[128 + t] + partB[192 + t];

        // sumMu slice (p = quad*16+i), redundant per thread
        float sMu[16];
#pragma unroll
        for (int i = 0; i < 16; ++i) {
            const int p = quad * 16 + i;
            sMu[i] = pm[p] + pm[64 + p] + pm[128 + p] + pm[192 + p];
        }
        // s2[q] = sumMu @ W2[q,:]  (fp32, quad-split + shfl combine)
        float s2[4];
#pragma unroll
        for (int qt = 0; qt < 4; ++qt) {
            float s = 0.f;
#pragma unroll
            for (int c = 0; c < 4; ++c) {
                f32x4 wv = *(const f32x4*)&W2g[(qt * 16 + l15) * 64 + quad * 16 + c * 4];
#pragma unroll
                for (int e = 0; e < 4; ++e) s += sMu[c*4+e] * wv[e];
            }
            s += __shfl_xor(s, 16); s += __shfl_xor(s, 32);
            s2[qt] = s;
        }

        float psum[4] = {0.f, 0.f, 0.f, 0.f};
#pragma unroll
        for (int kt = 0; kt < 2; ++kt) {
            const int krow = w * 32 + kt * 16 + l15;
            bf16x8 a0 = *(bf16x8*)&muS[krow * 72 + quad * 8];
            bf16x8 a1 = *(bf16x8*)&muS[krow * 72 + 32 + quad * 8];
#pragma unroll
            for (int qt = 0; qt < 4; ++qt) {
                f32x4 acc = MFMA16(a0, bW2[qt][0], zero4);
                acc = MFMA16(a1, bW2[qt][1], acc);
#pragma unroll
                for (int r = 0; r < 4; ++r) {
                    const int k = w * 32 + kt * 16 + quad * 4 + r;
                    float v = fmaxf(baseR[kt][qt][r] + s2[qt] - acc[r], 0.f);
                    bf16 h = (bf16)v;
                    muS[k * 72 + qt * 16 + l15] = h;
                    psum[qt] += (float)h;
                }
            }
        }
#pragma unroll
        for (int qt = 0; qt < 4; ++qt) {
            float p = psum[qt];
            p += __shfl_xor(p, 16); p += __shfl_xor(p, 32);
            if (lane < 16) pmN[w * 64 + qt * 16 + lane] = p;
        }
        __syncthreads();
    }

    // ---------------- readout ----------------
    {
        const float* pm = partMu[1];   // (3)&1
        float pp = 0.f;
#pragma unroll
        for (int c = 0; c < 4; ++c) {
            f32x4 wv = *(const f32x4*)&W6g[lane * 64 + w * 16 + c * 4];
#pragma unroll
            for (int e = 0; e < 4; ++e) {
                const int p = w * 16 + c * 4 + e;
                float sm4 = pm[p] + pm[64 + p] + pm[128 + p] + pm[192 + p];
                pp += sm4 * wv[e];
            }
        }
        partA[w * 64 + lane] = pp;
    }
    __syncthreads();

    float qa = 0.f;
#pragma unroll
    for (int i = 0; i < 16; ++i) {
        const int q = quad * 16 + i;
        float pl = fmaxf(partA[q] + partA[64 + q] + partA[128 + q] + partA[192 + q], 0.f);
        qa += pl * W5s[q];
    }
    qa += __shfl_xor(qa, 16); qa += __shfl_xor(qa, 32);

    if (t < 128) {
        float accq = qa;
#pragma unroll
        for (int j = 0; j < 8; ++j) {
            bf16x8 m8 = *(bf16x8*)&muS[t * 72 + j * 8];
#pragma unroll
            for (int e = 0; e < 8; ++e) accq += (float)m8[e] * uS[j * 8 + e];
        }
        Outg[b * 128 + t] = accq;
    }
}

extern "C" void kernel_launch(void* const* d_in, const int* in_sizes, int n_in,
                              void* d_out, int out_size, void* d_ws, size_t ws_size,
                              hipStream_t stream) {
    (void)n_in; (void)d_ws; (void)ws_size; (void)out_size;
    const int B = in_sizes[0] >> 7;   // 4096
    qnet_kernel<<<B, 256, 0, stream>>>(
        (const float*)d_in[0], (const float*)d_in[1], (const float*)d_in[2],
        (const float*)d_in[3], (const float*)d_in[4], (const float*)d_in[5],
        (const float*)d_in[6], (const float*)d_in[7], (const float*)d_in[8],
        (float*)d_out);
}

// Round 3
// 243.881 us; speedup vs baseline: 1.2723x; 1.2723x over previous
//
#include <hip/hip_runtime.h>

typedef __bf16 bf16;
typedef __bf16 bf16x8 __attribute__((ext_vector_type(8)));
typedef float  f32x4  __attribute__((ext_vector_type(4)));

#define MFMA16(a, b, c) __builtin_amdgcn_mfma_f32_16x16x32_bf16((a), (b), (c), 0, 0, 0)

// One block per batch element. 256 threads = 4 waves; wave w owns k-rows [32w,32w+32).
// LDS ~24.5KB -> up to 6 blocks/CU by LDS; occupancy set by natural VGPR use (~90-120).
// NOTE: __launch_bounds__(256,2) — R2's (256,5) capped VGPRs at ~102 and the ~110-reg
// live set (bW2 32 + baseR 32 + working) spilled to scratch: 160MB/178MB HBM traffic,
// 2.6x regression. Do not re-tighten without trimming the live set first.
__global__ __launch_bounds__(256, 2)
void qnet_kernel(const float* __restrict__ Xg, const float* __restrict__ Wg,
                 const float* __restrict__ W1g, const float* __restrict__ W2g,
                 const float* __restrict__ W3g, const float* __restrict__ W4g,
                 const float* __restrict__ W5g, const float* __restrict__ W6g,
                 const float* __restrict__ W7g, float* __restrict__ Outg)
{
    __shared__ __align__(16) bf16 muS[128 * 72];   // mu, bf16, row stride 72 (b128-aligned rows)
    __shared__ float xs[128], wws[128], W5s[128];
    __shared__ float partMu[2][256];               // ping-pong per-wave column sums
    __shared__ float partA[256], partB[256];
    __shared__ float uS[64];

    const int t    = threadIdx.x;
    const int b    = blockIdx.x;
    const int lane = t & 63;
    const int w    = t >> 6;
    const int l15  = lane & 15;
    const int quad = lane >> 4;

    // ---------------- stage per-batch vectors ----------------
    if (t < 128) { xs[t] = Xg[b * 128 + t]; W5s[t] = W5g[t]; }
    else         wws[t - 128] = Wg[b * 128 + t - 128];
    __syncthreads();

    // ---------------- phase B: closed-form tmsg terms (exact fp32) ----------------
    float Ap, Bn;
    {
        float w0 = wws[lane], w1 = wws[64 + lane];
        Ap = fmaxf(w0, 0.f) + fmaxf(w1, 0.f);
        Bn = fmaxf(-w0, 0.f) + fmaxf(-w1, 0.f);
#pragma unroll
        for (int m = 1; m < 64; m <<= 1) { Ap += __shfl_xor(Ap, m); Bn += __shfl_xor(Bn, m); }
    }

    // relu(+/-W4) slice for p = quad*16 + i
    float r4p[16], r4m[16];
#pragma unroll
    for (int c = 0; c < 4; ++c) {
        f32x4 v = *(const f32x4*)&W4g[quad * 16 + c * 4];
#pragma unroll
        for (int e = 0; e < 4; ++e) { r4p[c*4+e] = fmaxf(v[e], 0.f); r4m[c*4+e] = fmaxf(-v[e], 0.f); }
    }

    // v3p[q]=relu(W4)@W3[q,:], v3m[q]=relu(-W4)@W3[q,:]; st3[q]=Ap*v3p+Bn*v3m (= sum_t@W3^T)
    float v3p[4], v3m[4], st3[4], W1r[4];
#pragma unroll
    for (int qt = 0; qt < 4; ++qt) {
        const int q = qt * 16 + l15;
        float sp = 0.f, sm = 0.f;
#pragma unroll
        for (int c = 0; c < 4; ++c) {
            f32x4 wv = *(const f32x4*)&W3g[q * 64 + quad * 16 + c * 4];
#pragma unroll
            for (int e = 0; e < 4; ++e) { sp += r4p[c*4+e] * wv[e]; sm += r4m[c*4+e] * wv[e]; }
        }
        sp += __shfl_xor(sp, 16); sp += __shfl_xor(sp, 32);
        sm += __shfl_xor(sm, 16); sm += __shfl_xor(sm, 32);
        v3p[qt] = sp; v3m[qt] = sm;
        st3[qt] = Ap * sp + Bn * sm;
        W1r[qt] = W1g[q];
    }

    // u = W5b @ W7 partials (q-slice per wave)
    {
        float su = 0.f;
#pragma unroll
        for (int i = 0; i < 16; ++i)
            su += W5s[64 + w * 16 + i] * W7g[(w * 16 + i) * 64 + lane];
        partB[w * 64 + lane] = su;
    }

    // W2 B-fragments (bf16) straight from global (L1/L2-hot, shared by all blocks)
    bf16x8 bW2[4][2];
#pragma unroll
    for (int qt = 0; qt < 4; ++qt)
#pragma unroll
        for (int s = 0; s < 2; ++s) {
            f32x4 f0 = *(const f32x4*)&W2g[(qt * 16 + l15) * 64 + s * 32 + quad * 8];
            f32x4 f1 = *(const f32x4*)&W2g[(qt * 16 + l15) * 64 + s * 32 + quad * 8 + 4];
            bf16x8 h;
#pragma unroll
            for (int e = 0; e < 4; ++e) { h[e] = (bf16)f0[e]; h[4 + e] = (bf16)f1[e]; }
            bW2[qt][s] = h;
        }

    // mu1 = relu(base), base exact fp32 in registers (C-fragment layout)
    float baseR[2][4][4];
    {
        float psum[4] = {0.f, 0.f, 0.f, 0.f};
#pragma unroll
        for (int kt = 0; kt < 2; ++kt) {
            float xk[4], ak[4], bk[4];
#pragma unroll
            for (int r = 0; r < 4; ++r) {
                const int k = w * 32 + kt * 16 + quad * 4 + r;
                xk[r] = xs[k];
                float wk = wws[k];
                ak[r] = fmaxf(wk, 0.f); bk[r] = fmaxf(-wk, 0.f);
            }
#pragma unroll
            for (int qt = 0; qt < 4; ++qt)
#pragma unroll
                for (int r = 0; r < 4; ++r) {
                    float bb = xk[r] * W1r[qt] + st3[qt] - (ak[r] * v3p[qt] + bk[r] * v3m[qt]);
                    baseR[kt][qt][r] = bb;
                    bf16 h = (bf16)fmaxf(bb, 0.f);
                    const int k = w * 32 + kt * 16 + quad * 4 + r;
                    muS[k * 72 + qt * 16 + l15] = h;
                    psum[qt] += (float)h;
                }
        }
#pragma unroll
        for (int qt = 0; qt < 4; ++qt) {
            float p = psum[qt];
            p += __shfl_xor(p, 16); p += __shfl_xor(p, 32);
            if (lane < 16) partMu[0][w * 64 + qt * 16 + lane] = p;
        }
    }
    __syncthreads();

    // ---------------- 3 message-passing iterations, ONE barrier each ----------------
    const f32x4 zero4 = {0.f, 0.f, 0.f, 0.f};
    for (int it = 0; it < 3; ++it) {
        const float* pm  = partMu[it & 1];
        float*       pmN = partMu[(it + 1) & 1];
        if (it == 0 && t < 64)
            uS[t] = partB[t] + partB[64 + t] + partB[128 + t] + partB[192 + t];

        // sumMu slice (p = quad*16+i), redundant per thread
        float sMu[16];
#pragma unroll
        for (int i = 0; i < 16; ++i) {
            const int p = quad * 16 + i;
            sMu[i] = pm[p] + pm[64 + p] + pm[128 + p] + pm[192 + p];
        }
        // s2[q] = sumMu @ W2[q,:]  (fp32, quad-split + shfl combine)
        float s2[4];
#pragma unroll
        for (int qt = 0; qt < 4; ++qt) {
            float s = 0.f;
#pragma unroll
            for (int c = 0; c < 4; ++c) {
                f32x4 wv = *(const f32x4*)&W2g[(qt * 16 + l15) * 64 + quad * 16 + c * 4];
#pragma unroll
                for (int e = 0; e < 4; ++e) s += sMu[c*4+e] * wv[e];
            }
            s += __shfl_xor(s, 16); s += __shfl_xor(s, 32);
            s2[qt] = s;
        }

        float psum[4] = {0.f, 0.f, 0.f, 0.f};
#pragma unroll
        for (int kt = 0; kt < 2; ++kt) {
            const int krow = w * 32 + kt * 16 + l15;
            bf16x8 a0 = *(bf16x8*)&muS[krow * 72 + quad * 8];
            bf16x8 a1 = *(bf16x8*)&muS[krow * 72 + 32 + quad * 8];
#pragma unroll
            for (int qt = 0; qt < 4; ++qt) {
                f32x4 acc = MFMA16(a0, bW2[qt][0], zero4);
                acc = MFMA16(a1, bW2[qt][1], acc);
#pragma unroll
                for (int r = 0; r < 4; ++r) {
                    const int k = w * 32 + kt * 16 + quad * 4 + r;
                    float v = fmaxf(baseR[kt][qt][r] + s2[qt] - acc[r], 0.f);
                    bf16 h = (bf16)v;
                    muS[k * 72 + qt * 16 + l15] = h;
                    psum[qt] += (float)h;
                }
            }
        }
#pragma unroll
        for (int qt = 0; qt < 4; ++qt) {
            float p = psum[qt];
            p += __shfl_xor(p, 16); p += __shfl_xor(p, 32);
            if (lane < 16) pmN[w * 64 + qt * 16 + lane] = p;
        }
        __syncthreads();
    }

    // ---------------- readout ----------------
    {
        const float* pm = partMu[1];   // (3)&1
        float pp = 0.f;
#pragma unroll
        for (int c = 0; c < 4; ++c) {
            f32x4 wv = *(const f32x4*)&W6g[lane * 64 + w * 16 + c * 4];
#pragma unroll
            for (int e = 0; e < 4; ++e) {
                const int p = w * 16 + c * 4 + e;
                float sm4 = pm[p] + pm[64 + p] + pm[128 + p] + pm[192 + p];
                pp += sm4 * wv[e];
            }
        }
        partA[w * 64 + lane] = pp;
    }
    __syncthreads();

    float qa = 0.f;
#pragma unroll
    for (int i = 0; i < 16; ++i) {
        const int q = quad * 16 + i;
        float pl = fmaxf(partA[q] + partA[64 + q] + partA[128 + q] + partA[192 + q], 0.f);
        qa += pl * W5s[q];
    }
    qa += __shfl_xor(qa, 16); qa += __shfl_xor(qa, 32);

    if (t < 128) {
        float accq = qa;
#pragma unroll
        for (int j = 0; j < 8; ++j) {
            bf16x8 m8 = *(bf16x8*)&muS[t * 72 + j * 8];
#pragma unroll
            for (int e = 0; e < 8; ++e) accq += (float)m8[e] * uS[j * 8 + e];
        }
        Outg[b * 128 + t] = accq;
    }
}

extern "C" void kernel_launch(void* const* d_in, const int* in_sizes, int n_in,
                              void* d_out, int out_size, void* d_ws, size_t ws_size,
                              hipStream_t stream) {
    (void)n_in; (void)d_ws; (void)ws_size; (void)out_size;
    const int B = in_sizes[0] >> 7;   // 4096
    qnet_kernel<<<B, 256, 0, stream>>>(
        (const float*)d_in[0], (const float*)d_in[1], (const float*)d_in[2],
        (const float*)d_in[3], (const float*)d_in[4], (const float*)d_in[5],
        (const float*)d_in[6], (const float*)d_in[7], (const float*)d_in[8],
        (float*)d_out);
}

// Round 4
// 166.257 us; speedup vs baseline: 1.8663x; 1.4669x over previous
//
#include <hip/hip_runtime.h>

typedef __bf16 bf16;
typedef __bf16 bf16x8 __attribute__((ext_vector_type(8)));
typedef float  f32x4  __attribute__((ext_vector_type(4)));

#define MFMA16(a, b, c) __builtin_amdgcn_mfma_f32_16x16x32_bf16((a), (b), (c), 0, 0, 0)

// One block per batch element. 256 threads = 4 waves; wave w owns k-rows [32w,32w+32).
// R4: R1's LDS-resident iteration body (W2f fp32 in LDS, two-step sumMu) + R3's
// closed-form prologue. LDS ~38.3KB -> 4 blocks/CU. launch_bounds(256,4) caps VGPR
// at 128 (natural ~88; R2 showed capping below the live set (102 vs ~110) spills
// catastrophically -- 160MB scratch traffic. 128 cap is safe).
__global__ __launch_bounds__(256, 4)
void qnet_kernel(const float* __restrict__ Xg, const float* __restrict__ Wg,
                 const float* __restrict__ W1g, const float* __restrict__ W2g,
                 const float* __restrict__ W3g, const float* __restrict__ W4g,
                 const float* __restrict__ W5g, const float* __restrict__ W6g,
                 const float* __restrict__ W7g, float* __restrict__ Outg)
{
    __shared__ __align__(16) bf16 muS[128 * 72];   // 18432 B, row stride 72 (b128 rows, 2-way max)
    __shared__ float W2f[64 * 65];                 // 16640 B, fp32 W2 for s2 matvec
    __shared__ float xs[128], wws[128], W5s[128];  // 1536 B
    __shared__ float partMu[256];                  // 1024 B
    __shared__ float partAB[256];                  // 1024 B (u-partials in prologue, pooled partials in readout)
    __shared__ float sumMuS[64];                   // 256 B
    __shared__ float uS[64];                       // 256 B

    const int t    = threadIdx.x;
    const int b    = blockIdx.x;
    const int lane = t & 63;
    const int w    = t >> 6;
    const int l15  = lane & 15;
    const int quad = lane >> 4;

    // ---------------- stage: per-batch vectors + W2 fp32 into LDS ----------------
    if (t < 128) { xs[t] = Xg[b * 128 + t]; W5s[t] = W5g[t]; }
    else         wws[t - 128] = Wg[b * 128 + t - 128];
    {
        const int q = t >> 2, pb = (t & 3) << 4;   // row q, 16-col chunk
#pragma unroll
        for (int c = 0; c < 4; ++c) {
            f32x4 v = *(const f32x4*)&W2g[q * 64 + pb + c * 4];
#pragma unroll
            for (int e = 0; e < 4; ++e) W2f[q * 65 + pb + c * 4 + e] = v[e];
        }
    }
    __syncthreads();

    // ---------------- prologue: closed-form tmsg terms (exact fp32) ----------------
    float Ap, Bn;
    {
        float w0 = wws[lane], w1 = wws[64 + lane];
        Ap = fmaxf(w0, 0.f) + fmaxf(w1, 0.f);
        Bn = fmaxf(-w0, 0.f) + fmaxf(-w1, 0.f);
#pragma unroll
        for (int m = 1; m < 64; m <<= 1) { Ap += __shfl_xor(Ap, m); Bn += __shfl_xor(Bn, m); }
    }

    float r4p[16], r4m[16];
#pragma unroll
    for (int c = 0; c < 4; ++c) {
        f32x4 v = *(const f32x4*)&W4g[quad * 16 + c * 4];
#pragma unroll
        for (int e = 0; e < 4; ++e) { r4p[c*4+e] = fmaxf(v[e], 0.f); r4m[c*4+e] = fmaxf(-v[e], 0.f); }
    }

    // v3p[q]=relu(W4)@W3[q,:], v3m[q]=relu(-W4)@W3[q,:]; st3 = Ap*v3p + Bn*v3m
    float v3p[4], v3m[4], st3[4], W1r[4];
#pragma unroll
    for (int qt = 0; qt < 4; ++qt) {
        const int q = qt * 16 + l15;
        float sp = 0.f, sm = 0.f;
#pragma unroll
        for (int c = 0; c < 4; ++c) {
            f32x4 wv = *(const f32x4*)&W3g[q * 64 + quad * 16 + c * 4];
#pragma unroll
            for (int e = 0; e < 4; ++e) { sp += r4p[c*4+e] * wv[e]; sm += r4m[c*4+e] * wv[e]; }
        }
        sp += __shfl_xor(sp, 16); sp += __shfl_xor(sp, 32);
        sm += __shfl_xor(sm, 16); sm += __shfl_xor(sm, 32);
        v3p[qt] = sp; v3m[qt] = sm;
        st3[qt] = Ap * sp + Bn * sm;
        W1r[qt] = W1g[q];
    }

    // u = W5b @ W7 partials (q-slice per wave) -> partAB
    {
        float su = 0.f;
#pragma unroll
        for (int i = 0; i < 16; ++i)
            su += W5s[64 + w * 16 + i] * W7g[(w * 16 + i) * 64 + lane];
        partAB[w * 64 + lane] = su;
    }

    // W2 B-fragments (bf16) into registers, from global (one-time, L2-hot)
    bf16x8 bW2[4][2];
#pragma unroll
    for (int qt = 0; qt < 4; ++qt)
#pragma unroll
        for (int s = 0; s < 2; ++s) {
            f32x4 f0 = *(const f32x4*)&W2g[(qt * 16 + l15) * 64 + s * 32 + quad * 8];
            f32x4 f1 = *(const f32x4*)&W2g[(qt * 16 + l15) * 64 + s * 32 + quad * 8 + 4];
            bf16x8 h;
#pragma unroll
            for (int e = 0; e < 4; ++e) { h[e] = (bf16)f0[e]; h[4 + e] = (bf16)f1[e]; }
            bW2[qt][s] = h;
        }

    // mu1 = relu(base), base exact fp32 in registers (C-fragment layout)
    float baseR[2][4][4];
    {
        float psum[4] = {0.f, 0.f, 0.f, 0.f};
#pragma unroll
        for (int kt = 0; kt < 2; ++kt) {
            float xk[4], ak[4], bk[4];
#pragma unroll
            for (int r = 0; r < 4; ++r) {
                const int k = w * 32 + kt * 16 + quad * 4 + r;
                xk[r] = xs[k];
                float wk = wws[k];
                ak[r] = fmaxf(wk, 0.f); bk[r] = fmaxf(-wk, 0.f);
            }
#pragma unroll
            for (int qt = 0; qt < 4; ++qt)
#pragma unroll
                for (int r = 0; r < 4; ++r) {
                    float bb = xk[r] * W1r[qt] + st3[qt] - (ak[r] * v3p[qt] + bk[r] * v3m[qt]);
                    baseR[kt][qt][r] = bb;
                    bf16 h = (bf16)fmaxf(bb, 0.f);
                    const int k = w * 32 + kt * 16 + quad * 4 + r;
                    muS[k * 72 + qt * 16 + l15] = h;
                    psum[qt] += (float)h;
                }
        }
#pragma unroll
        for (int qt = 0; qt < 4; ++qt) {
            float p = psum[qt];
            p += __shfl_xor(p, 16); p += __shfl_xor(p, 32);
            if (lane < 16) partMu[w * 64 + qt * 16 + lane] = p;
        }
    }
    __syncthreads();

    // ---------------- 3 message-passing iterations (2 barriers each) ----------------
    const f32x4 zero4 = {0.f, 0.f, 0.f, 0.f};
    for (int it = 0; it < 3; ++it) {
        // [A] reduce partMu -> sumMuS (t<64); finalize uS once
        if (t < 64) {
            sumMuS[t] = partMu[t] + partMu[64 + t] + partMu[128 + t] + partMu[192 + t];
            if (it == 0)
                uS[t] = partAB[t] + partAB[64 + t] + partAB[128 + t] + partAB[192 + t];
        }
        __syncthreads();

        // [B] mu fragments (independent of s2 chain -> overlaps)
        bf16x8 a0[2], a1[2];
#pragma unroll
        for (int kt = 0; kt < 2; ++kt) {
            const int krow = w * 32 + kt * 16 + l15;
            a0[kt] = *(bf16x8*)&muS[krow * 72 + quad * 8];
            a1[kt] = *(bf16x8*)&muS[krow * 72 + 32 + quad * 8];
        }
        f32x4 acc[2][4];
#pragma unroll
        for (int kt = 0; kt < 2; ++kt)
#pragma unroll
            for (int qt = 0; qt < 4; ++qt) {
                acc[kt][qt] = MFMA16(a0[kt], bW2[qt][0], zero4);
                acc[kt][qt] = MFMA16(a1[kt], bW2[qt][1], acc[kt][qt]);
            }

        // s2[q] = sumMu @ W2[q,:] in fp32 (LDS-only, quad-split + shfl)
        float sMu[16];
#pragma unroll
        for (int i = 0; i < 16; ++i) sMu[i] = sumMuS[quad * 16 + i];
        float s2[4];
#pragma unroll
        for (int qt = 0; qt < 4; ++qt) {
            float s = 0.f;
            const int row = (qt * 16 + l15) * 65 + quad * 16;
#pragma unroll
            for (int c = 0; c < 4; ++c)
#pragma unroll
                for (int e = 0; e < 4; ++e) s += sMu[c*4+e] * W2f[row + c * 4 + e];
            s += __shfl_xor(s, 16); s += __shfl_xor(s, 32);
            s2[qt] = s;
        }

        float psum[4] = {0.f, 0.f, 0.f, 0.f};
#pragma unroll
        for (int kt = 0; kt < 2; ++kt)
#pragma unroll
            for (int qt = 0; qt < 4; ++qt)
#pragma unroll
                for (int r = 0; r < 4; ++r) {
                    const int k = w * 32 + kt * 16 + quad * 4 + r;
                    float v = fmaxf(baseR[kt][qt][r] + s2[qt] - acc[kt][qt][r], 0.f);
                    bf16 h = (bf16)v;
                    muS[k * 72 + qt * 16 + l15] = h;
                    psum[qt] += (float)h;
                }
#pragma unroll
        for (int qt = 0; qt < 4; ++qt) {
            float p = psum[qt];
            p += __shfl_xor(p, 16); p += __shfl_xor(p, 32);
            if (lane < 16) partMu[w * 64 + qt * 16 + lane] = p;
        }
        __syncthreads();
    }

    // ---------------- readout ----------------
    if (t < 64)
        sumMuS[t] = partMu[t] + partMu[64 + t] + partMu[128 + t] + partMu[192 + t];
    __syncthreads();

    {
        float pp = 0.f;
#pragma unroll
        for (int c = 0; c < 4; ++c) {
            f32x4 wv = *(const f32x4*)&W6g[lane * 64 + w * 16 + c * 4];
#pragma unroll
            for (int e = 0; e < 4; ++e) pp += sumMuS[w * 16 + c * 4 + e] * wv[e];
        }
        partAB[w * 64 + lane] = pp;
    }
    __syncthreads();

    float qa = 0.f;
#pragma unroll
    for (int i = 0; i < 16; ++i) {
        const int q = quad * 16 + i;
        float pl = fmaxf(partAB[q] + partAB[64 + q] + partAB[128 + q] + partAB[192 + q], 0.f);
        qa += pl * W5s[q];
    }
    qa += __shfl_xor(qa, 16); qa += __shfl_xor(qa, 32);

    if (t < 128) {
        float accq = qa;
#pragma unroll
        for (int j = 0; j < 8; ++j) {
            bf16x8 m8 = *(bf16x8*)&muS[t * 72 + j * 8];
#pragma unroll
            for (int e = 0; e < 8; ++e) accq += (float)m8[e] * uS[j * 8 + e];
        }
        Outg[b * 128 + t] = accq;
    }
}

extern "C" void kernel_launch(void* const* d_in, const int* in_sizes, int n_in,
                              void* d_out, int out_size, void* d_ws, size_t ws_size,
                              hipStream_t stream) {
    (void)n_in; (void)d_ws; (void)ws_size; (void)out_size;
    const int B = in_sizes[0] >> 7;   // 4096
    qnet_kernel<<<B, 256, 0, stream>>>(
        (const float*)d_in[0], (const float*)d_in[1], (const float*)d_in[2],
        (const float*)d_in[3], (const float*)d_in[4], (const float*)d_in[5],
        (const float*)d_in[6], (const float*)d_in[7], (const float*)d_in[8],
        (float*)d_out);
}

// Round 5
// 160.852 us; speedup vs baseline: 1.9291x; 1.0336x over previous
//
#include <hip/hip_runtime.h>

typedef __bf16 bf16;
typedef __bf16 bf16x8 __attribute__((ext_vector_type(8)));
typedef float  f32x4  __attribute__((ext_vector_type(4)));

#define MFMA16(a, b, c) __builtin_amdgcn_mfma_f32_16x16x32_bf16((a), (b), (c), 0, 0, 0)

// One block per batch element. 256 threads = 4 waves; wave w owns k-rows [32w,32w+32).
// R5: s2 matvec via distributed fp32 W2 rows in registers (lane=q, wave=p-slice):
// partMu read as wave-uniform b128 broadcasts (fuses sumMu reduce into matvec),
// W2f LDS buffer deleted -> LDS ~24.3KB. launch_bounds(256,2): NEVER cap VGPR below
// the live set (R2: 102-cap -> 160MB scratch; R4: (256,4) squeezed to 64 VGPR -> 24MB).
__global__ __launch_bounds__(256, 2)
void qnet_kernel(const float* __restrict__ Xg, const float* __restrict__ Wg,
                 const float* __restrict__ W1g, const float* __restrict__ W2g,
                 const float* __restrict__ W3g, const float* __restrict__ W4g,
                 const float* __restrict__ W5g, const float* __restrict__ W6g,
                 const float* __restrict__ W7g, float* __restrict__ Outg)
{
    __shared__ __align__(16) bf16 muS[128 * 72];   // 18432 B, row stride 72
    __shared__ float xs[128], wws[128], W5s[128];  // 1536 B
    __shared__ __align__(16) float partMu[256];    // 1024 B  [w'][p]
    __shared__ __align__(16) float partS2[256];    // 1024 B  [q][w]
    __shared__ float partAB[256];                  // 1024 B  (u-partials, then pooled partials)
    __shared__ float sumMuS[64];                   // 256 B
    __shared__ float uS[64];                       // 256 B

    const int t    = threadIdx.x;
    const int b    = blockIdx.x;
    const int lane = t & 63;
    const int w    = t >> 6;
    const int l15  = lane & 15;
    const int quad = lane >> 4;

    // ---------------- stage per-batch vectors ----------------
    if (t < 128) { xs[t] = Xg[b * 128 + t]; W5s[t] = W5g[t]; }
    else         wws[t - 128] = Wg[b * 128 + t - 128];
    __syncthreads();

    // ---------------- prologue: closed-form tmsg terms (exact fp32) ----------------
    float Ap, Bn;
    {
        float w0 = wws[lane], w1 = wws[64 + lane];
        Ap = fmaxf(w0, 0.f) + fmaxf(w1, 0.f);
        Bn = fmaxf(-w0, 0.f) + fmaxf(-w1, 0.f);
#pragma unroll
        for (int m = 1; m < 64; m <<= 1) { Ap += __shfl_xor(Ap, m); Bn += __shfl_xor(Bn, m); }
    }

    float r4p[16], r4m[16];
#pragma unroll
    for (int c = 0; c < 4; ++c) {
        f32x4 v = *(const f32x4*)&W4g[quad * 16 + c * 4];
#pragma unroll
        for (int e = 0; e < 4; ++e) { r4p[c*4+e] = fmaxf(v[e], 0.f); r4m[c*4+e] = fmaxf(-v[e], 0.f); }
    }

    // v3p[q]=relu(W4)@W3[q,:], v3m[q]=relu(-W4)@W3[q,:]; st3 = Ap*v3p + Bn*v3m
    float v3p[4], v3m[4], st3[4], W1r[4];
#pragma unroll
    for (int qt = 0; qt < 4; ++qt) {
        const int q = qt * 16 + l15;
        float sp = 0.f, sm = 0.f;
#pragma unroll
        for (int c = 0; c < 4; ++c) {
            f32x4 wv = *(const f32x4*)&W3g[q * 64 + quad * 16 + c * 4];
#pragma unroll
            for (int e = 0; e < 4; ++e) { sp += r4p[c*4+e] * wv[e]; sm += r4m[c*4+e] * wv[e]; }
        }
        sp += __shfl_xor(sp, 16); sp += __shfl_xor(sp, 32);
        sm += __shfl_xor(sm, 16); sm += __shfl_xor(sm, 32);
        v3p[qt] = sp; v3m[qt] = sm;
        st3[qt] = Ap * sp + Bn * sm;
        W1r[qt] = W1g[q];
    }

    // u = W5b @ W7 partials (q-slice per wave) -> partAB
    {
        float su = 0.f;
#pragma unroll
        for (int i = 0; i < 16; ++i)
            su += W5s[64 + w * 16 + i] * W7g[(w * 16 + i) * 64 + lane];
        partAB[w * 64 + lane] = su;
    }

    // fp32 W2 row q=lane, p-slice [16w,16w+16) in registers (for s2 matvec)
    float w2row[16];
#pragma unroll
    for (int c = 0; c < 4; ++c) {
        f32x4 v = *(const f32x4*)&W2g[lane * 64 + w * 16 + c * 4];
#pragma unroll
        for (int e = 0; e < 4; ++e) w2row[c*4+e] = v[e];
    }

    // W2 B-fragments (bf16) into registers (one-time, L2-hot)
    bf16x8 bW2[4][2];
#pragma unroll
    for (int qt = 0; qt < 4; ++qt)
#pragma unroll
        for (int s = 0; s < 2; ++s) {
            f32x4 f0 = *(const f32x4*)&W2g[(qt * 16 + l15) * 64 + s * 32 + quad * 8];
            f32x4 f1 = *(const f32x4*)&W2g[(qt * 16 + l15) * 64 + s * 32 + quad * 8 + 4];
            bf16x8 h;
#pragma unroll
            for (int e = 0; e < 4; ++e) { h[e] = (bf16)f0[e]; h[4 + e] = (bf16)f1[e]; }
            bW2[qt][s] = h;
        }

    // mu1 = relu(base), base exact fp32 in registers (C-fragment layout)
    float baseR[2][4][4];
    {
        float psum[4] = {0.f, 0.f, 0.f, 0.f};
#pragma unroll
        for (int kt = 0; kt < 2; ++kt) {
            float xk[4], ak[4], bk[4];
#pragma unroll
            for (int r = 0; r < 4; ++r) {
                const int k = w * 32 + kt * 16 + quad * 4 + r;
                xk[r] = xs[k];
                float wk = wws[k];
                ak[r] = fmaxf(wk, 0.f); bk[r] = fmaxf(-wk, 0.f);
            }
#pragma unroll
            for (int qt = 0; qt < 4; ++qt)
#pragma unroll
                for (int r = 0; r < 4; ++r) {
                    float bb = xk[r] * W1r[qt] + st3[qt] - (ak[r] * v3p[qt] + bk[r] * v3m[qt]);
                    baseR[kt][qt][r] = bb;
                    bf16 h = (bf16)fmaxf(bb, 0.f);
                    const int k = w * 32 + kt * 16 + quad * 4 + r;
                    muS[k * 72 + qt * 16 + l15] = h;
                    psum[qt] += (float)h;
                }
        }
#pragma unroll
        for (int qt = 0; qt < 4; ++qt) {
            float p = psum[qt];
            p += __shfl_xor(p, 16); p += __shfl_xor(p, 32);
            if (lane < 16) partMu[w * 64 + qt * 16 + lane] = p;
        }
    }
    __syncthreads();

    // ---------------- 3 message-passing iterations (2 barriers each) ----------------
    const f32x4 zero4 = {0.f, 0.f, 0.f, 0.f};
    for (int it = 0; it < 3; ++it) {
        // [A] mu fragments (muS rows are wave-private -> valid here, overlaps barrier)
        bf16x8 a0[2], a1[2];
#pragma unroll
        for (int kt = 0; kt < 2; ++kt) {
            const int krow = w * 32 + kt * 16 + l15;
            a0[kt] = *(bf16x8*)&muS[krow * 72 + quad * 8];
            a1[kt] = *(bf16x8*)&muS[krow * 72 + 32 + quad * 8];
        }
        // s2 partial: wave-uniform b128 broadcasts of partMu, fused 4-way reduce + FMA
        {
            float sPart = 0.f;
#pragma unroll
            for (int c = 0; c < 4; ++c) {
                f32x4 r0 = *(const f32x4*)&partMu[       w * 16 + c * 4];
                f32x4 r1 = *(const f32x4*)&partMu[ 64 +  w * 16 + c * 4];
                f32x4 r2 = *(const f32x4*)&partMu[128 +  w * 16 + c * 4];
                f32x4 r3 = *(const f32x4*)&partMu[192 +  w * 16 + c * 4];
#pragma unroll
                for (int e = 0; e < 4; ++e)
                    sPart += (r0[e] + r1[e] + r2[e] + r3[e]) * w2row[c * 4 + e];
            }
            partS2[lane * 4 + w] = sPart;
        }
        __syncthreads();   // alpha: partS2 valid

        // [B] MFMA + s2 combine + epilogue
        f32x4 acc[2][4];
#pragma unroll
        for (int kt = 0; kt < 2; ++kt)
#pragma unroll
            for (int qt = 0; qt < 4; ++qt) {
                acc[kt][qt] = MFMA16(a0[kt], bW2[qt][0], zero4);
                acc[kt][qt] = MFMA16(a1[kt], bW2[qt][1], acc[kt][qt]);
            }

        float s2[4];
#pragma unroll
        for (int qt = 0; qt < 4; ++qt) {
            f32x4 p4 = *(const f32x4*)&partS2[(qt * 16 + l15) * 4];
            s2[qt] = (p4[0] + p4[1]) + (p4[2] + p4[3]);
        }

        float psum[4] = {0.f, 0.f, 0.f, 0.f};
#pragma unroll
        for (int kt = 0; kt < 2; ++kt)
#pragma unroll
            for (int qt = 0; qt < 4; ++qt)
#pragma unroll
                for (int r = 0; r < 4; ++r) {
                    const int k = w * 32 + kt * 16 + quad * 4 + r;
                    float v = fmaxf(baseR[kt][qt][r] + s2[qt] - acc[kt][qt][r], 0.f);
                    bf16 h = (bf16)v;
                    muS[k * 72 + qt * 16 + l15] = h;
                    psum[qt] += (float)h;
                }
#pragma unroll
        for (int qt = 0; qt < 4; ++qt) {
            float p = psum[qt];
            p += __shfl_xor(p, 16); p += __shfl_xor(p, 32);
            if (lane < 16) partMu[w * 64 + qt * 16 + lane] = p;
        }
        __syncthreads();   // beta: muS/partMu valid for next iter
    }

    // ---------------- readout ----------------
    if (t < 64) {
        sumMuS[t] = partMu[t] + partMu[64 + t] + partMu[128 + t] + partMu[192 + t];
        uS[t]     = partAB[t] + partAB[64 + t] + partAB[128 + t] + partAB[192 + t];
    }
    __syncthreads();

    {
        float pp = 0.f;
#pragma unroll
        for (int c = 0; c < 4; ++c) {
            f32x4 wv = *(const f32x4*)&W6g[lane * 64 + w * 16 + c * 4];
#pragma unroll
            for (int e = 0; e < 4; ++e) pp += sumMuS[w * 16 + c * 4 + e] * wv[e];
        }
        partAB[w * 64 + lane] = pp;
    }
    __syncthreads();

    float qa = 0.f;
#pragma unroll
    for (int i = 0; i < 16; ++i) {
        const int q = quad * 16 + i;
        float pl = fmaxf(partAB[q] + partAB[64 + q] + partAB[128 + q] + partAB[192 + q], 0.f);
        qa += pl * W5s[q];
    }
    qa += __shfl_xor(qa, 16); qa += __shfl_xor(qa, 32);

    if (t < 128) {
        float accq = qa;
#pragma unroll
        for (int j = 0; j < 8; ++j) {
            bf16x8 m8 = *(bf16x8*)&muS[t * 72 + j * 8];
#pragma unroll
            for (int e = 0; e < 8; ++e) accq += (float)m8[e] * uS[j * 8 + e];
        }
        Outg[b * 128 + t] = accq;
    }
}

extern "C" void kernel_launch(void* const* d_in, const int* in_sizes, int n_in,
                              void* d_out, int out_size, void* d_ws, size_t ws_size,
                              hipStream_t stream) {
    (void)n_in; (void)d_ws; (void)ws_size; (void)out_size;
    const int B = in_sizes[0] >> 7;   // 4096
    qnet_kernel<<<B, 256, 0, stream>>>(
        (const float*)d_in[0], (const float*)d_in[1], (const float*)d_in[2],
        (const float*)d_in[3], (const float*)d_in[4], (const float*)d_in[5],
        (const float*)d_in[6], (const float*)d_in[7], (const float*)d_in[8],
        (float*)d_out);
}